// Round 1
// baseline (645.781 us; speedup 1.0000x reference)
//
#include <hip/hip_runtime.h>
#include <math.h>

#define RESN  160
#define VOX   4096000          // 160^3
#define YSTR  160
#define ZSTR  25600            // 160*160
#define NPTS  478              // last sample index (0..478 inclusive = 479 samples)
#define NRAYS 2048

// unaligned-safe float2 (x-corner pairs are only 4B aligned)
typedef float f2_u __attribute__((ext_vector_type(2), aligned(4)));

__device__ __forceinline__ float plane_interior(const float* __restrict__ p,
                                                float w00, float w01, float w10, float w11,
                                                float wx0, float wx1)
{
    f2_u a = *(const f2_u*)(p);               // z0,y0,(x0,x1)
    f2_u b = *(const f2_u*)(p + YSTR);        // z0,y1
    f2_u c = *(const f2_u*)(p + ZSTR);        // z1,y0
    f2_u d = *(const f2_u*)(p + ZSTR + YSTR); // z1,y1
    float v0 = fmaf(a.y, wx1, a.x * wx0);
    float v1 = fmaf(b.y, wx1, b.x * wx0);
    float v2 = fmaf(c.y, wx1, c.x * wx0);
    float v3 = fmaf(d.y, wx1, d.x * wx0);
    return fmaf(v3, w11, fmaf(v2, w10, fmaf(v1, w01, v0 * w00)));
}

__global__ __launch_bounds__(64)
void plenoxel_render(const float* __restrict__ rays_o,
                     const float* __restrict__ rays_d,
                     const float* __restrict__ sig,
                     const float* __restrict__ rgb,
                     float* __restrict__ out)
{
    const int ray  = blockIdx.x;
    const int lane = threadIdx.x;

    const float ox = rays_o[ray*3+0], oy = rays_o[ray*3+1], oz = rays_o[ray*3+2];
    const float dxr = rays_d[ray*3+0], dyr = rays_d[ray*3+1], dzr = rays_d[ray*3+2];

    const float h = 2.6f * 1.7320508075688772f / 480.0f;   // voxel_len step

    // ---- start t (reference: max over axes of min((±1.3-o)/d), clip [0.2,6]) ----
    const float ax = (1.3f - ox) / dxr, bx = (-1.3f - ox) / dxr;
    const float ay = (1.3f - oy) / dyr, by = (-1.3f - oy) / dyr;
    const float az = (1.3f - oz) / dzr, bz = (-1.3f - oz) / dzr;
    float start = fmaxf(fmaxf(fminf(ax, bx), fminf(ay, by)), fminf(az, bz));
    start = fminf(fmaxf(start, 0.2f), 6.0f);

    // ---- in-box (with 1-voxel margin) sample range ----
    const float B = 1.3164f;  // covers fi in [-1, 160): any-corner-valid region
    const float mx1 = ( B - ox) / dxr, mx0 = (-B - ox) / dxr;
    const float my1 = ( B - oy) / dyr, my0 = (-B - oy) / dyr;
    const float mz1 = ( B - oz) / dzr, mz0 = (-B - oz) / dzr;
    float tl = fmaxf(fmaxf(fminf(mx0, mx1), fminf(my0, my1)), fminf(mz0, mz1));
    float th = fminf(fminf(fmaxf(mx0, mx1), fmaxf(my0, my1)), fmaxf(mz0, mz1));
    tl = fmaxf(tl, start);
    th = fminf(th, fmaf((float)NPTS, h, start));
    int s_lo, s_hi;
    if (th < tl) { s_lo = 0; s_hi = -1; }
    else {
        s_lo = max(0,    (int)floorf((tl - start) / h) - 1);
        s_hi = min(NPTS, (int)ceilf ((th - start) / h) + 1);
    }

    // ---- SH of normalized dir ----
    const float dsq  = dxr*dxr + dyr*dyr + dzr*dzr;
    const float dinv = rsqrtf(dsq);
    const float dn   = sqrtf(dsq);           // ||d||
    const float X = dxr * dinv, Y = dyr * dinv, Z = dzr * dinv;
    const float shv[9] = {
        0.28209479177387814f,
        -0.4886025119029199f * Y,
         0.4886025119029199f * Z,
        -0.4886025119029199f * X,
         1.0925484305920792f * X * Y,
        -1.0925484305920792f * Y * Z,
         0.31539156525252005f * (2.0f * Z * Z - X * X - Y * Y),
        -1.0925484305920792f * X * Z,
         0.5462742152960396f * (X * X - Y * Y),
    };
    const float dist = h * dn;               // constant per ray (diff of arithmetic seq)

    float accR = 0.f, accG = 0.f, accB = 0.f, accL = 0.f;
    float carry = 1.0f;

    for (int basei = s_lo; basei <= s_hi; basei += 64) {
        const int s = basei + lane;
        float alpha = 0.f, cr = 0.f, cg = 0.f, cb = 0.f;
        if (s <= s_hi) {
            const float t  = fmaf((float)s, h, start);
            const float px = fmaf(dxr, t, ox);
            const float py = fmaf(dyr, t, oy);
            const float pz = fmaf(dzr, t, oz);
            // fi = (p/1.3 + 1) * 79.5
            const float fx = fmaf(px, 61.153846153846f, 79.5f);
            const float fy = fmaf(py, 61.153846153846f, 79.5f);
            const float fz = fmaf(pz, 61.153846153846f, 79.5f);
            const float fxf = floorf(fx), fyf = floorf(fy), fzf = floorf(fz);
            const int   x0 = (int)fxf, y0 = (int)fyf, z0 = (int)fzf;
            const float wx1 = fx - fxf, wy1 = fy - fyf, wz1 = fz - fzf;
            const float wx0 = 1.f - wx1, wy0 = 1.f - wy1, wz0 = 1.f - wz1;

            float sv = 0.f, a0 = 0.f, a1 = 0.f, a2 = 0.f;

            if (x0 >= 0 && x0 <= 158 && y0 >= 0 && y0 <= 158 && z0 >= 0 && z0 <= 158) {
                // -------- interior fast path: 4x float2 per plane --------
                const float w00 = wz0*wy0, w01 = wz0*wy1, w10 = wz1*wy0, w11 = wz1*wy1;
                const size_t bofs = (size_t)z0 * ZSTR + (size_t)y0 * YSTR + (size_t)x0;
                sv = plane_interior(sig + bofs, w00, w01, w10, w11, wx0, wx1);
                const float* rp = rgb + bofs;
                #pragma unroll
                for (int c = 0; c < 3; ++c) {
                    float sc = 0.f;
                    #pragma unroll
                    for (int k = 0; k < 9; ++k) {
                        const float v = plane_interior(rp + (size_t)(c*9+k)*VOX,
                                                       w00, w01, w10, w11, wx0, wx1);
                        sc = fmaf(v, shv[k], sc);
                    }
                    if (c == 0) a0 = sc; else if (c == 1) a1 = sc; else a2 = sc;
                }
            } else {
                // -------- boundary path: per-corner masked scalar --------
                const float vwx0 = (x0   >= 0 && x0   < RESN) ? wx0 : 0.f;
                const float vwx1 = (x0+1 >= 0 && x0+1 < RESN) ? wx1 : 0.f;
                const float vwy0 = (y0   >= 0 && y0   < RESN) ? wy0 : 0.f;
                const float vwy1 = (y0+1 >= 0 && y0+1 < RESN) ? wy1 : 0.f;
                const float vwz0 = (z0   >= 0 && z0   < RESN) ? wz0 : 0.f;
                const float vwz1 = (z0+1 >= 0 && z0+1 < RESN) ? wz1 : 0.f;
                const int cx0 = min(max(x0,   0), RESN-1), cx1 = min(max(x0+1, 0), RESN-1);
                const int cy0 = min(max(y0,   0), RESN-1), cy1 = min(max(y0+1, 0), RESN-1);
                const int cz0 = min(max(z0,   0), RESN-1), cz1 = min(max(z0+1, 0), RESN-1);
                const float cw[8] = { vwz0*vwy0*vwx0, vwz0*vwy0*vwx1,
                                      vwz0*vwy1*vwx0, vwz0*vwy1*vwx1,
                                      vwz1*vwy0*vwx0, vwz1*vwy0*vwx1,
                                      vwz1*vwy1*vwx0, vwz1*vwy1*vwx1 };
                const size_t co[8] = {
                    (size_t)cz0*ZSTR + (size_t)cy0*YSTR + cx0,
                    (size_t)cz0*ZSTR + (size_t)cy0*YSTR + cx1,
                    (size_t)cz0*ZSTR + (size_t)cy1*YSTR + cx0,
                    (size_t)cz0*ZSTR + (size_t)cy1*YSTR + cx1,
                    (size_t)cz1*ZSTR + (size_t)cy0*YSTR + cx0,
                    (size_t)cz1*ZSTR + (size_t)cy0*YSTR + cx1,
                    (size_t)cz1*ZSTR + (size_t)cy1*YSTR + cx0,
                    (size_t)cz1*ZSTR + (size_t)cy1*YSTR + cx1 };
                #pragma unroll
                for (int j = 0; j < 8; ++j) {
                    if (cw[j] != 0.f) {
                        const float wj = cw[j];
                        sv = fmaf(sig[co[j]], wj, sv);
                        const float* rp = rgb + co[j];
                        float t0 = 0.f, t1 = 0.f, t2 = 0.f;
                        #pragma unroll
                        for (int k = 0; k < 9; ++k) {
                            t0 = fmaf(rp[(size_t)(k     )*VOX], shv[k], t0);
                            t1 = fmaf(rp[(size_t)(k +  9)*VOX], shv[k], t1);
                            t2 = fmaf(rp[(size_t)(k + 18)*VOX], shv[k], t2);
                        }
                        a0 = fmaf(t0, wj, a0);
                        a1 = fmaf(t1, wj, a1);
                        a2 = fmaf(t2, wj, a2);
                    }
                }
            }

            sv = fmaxf(sv, 0.f);                       // relu(sigma)
            alpha = 1.f - __expf(-sv * dist);
            cr = __fdividef(1.f, 1.f + __expf(-a0));   // sigmoid
            cg = __fdividef(1.f, 1.f + __expf(-a1));
            cb = __fdividef(1.f, 1.f + __expf(-a2));
        }

        // ---- wave-wide multiplicative scan of (1 - alpha + 1e-10) ----
        float m = (s <= s_hi) ? (1.f - alpha + 1e-10f) : 1.f;
        float incl = m;
        #pragma unroll
        for (int off = 1; off < 64; off <<= 1) {
            float nb = __shfl_up(incl, off);
            if (lane >= off) incl *= nb;
        }
        float excl = __shfl_up(incl, 1);
        if (lane == 0) excl = 1.f;

        const float T = carry * excl;
        const float w = T * alpha;                     // abs_light for this sample
        accR = fmaf(w, cr, accR);
        accG = fmaf(w, cg, accG);
        accB = fmaf(w, cb, accB);
        accL += w;
        carry *= __shfl(incl, 63);
    }

    // ---- wave reduction + white background ----
    #pragma unroll
    for (int off = 32; off; off >>= 1) {
        accR += __shfl_xor(accR, off);
        accG += __shfl_xor(accG, off);
        accB += __shfl_xor(accB, off);
        accL += __shfl_xor(accL, off);
    }
    if (lane == 0) {
        const float bg = 1.f - accL;
        out[ray*3+0] = accR + bg;
        out[ray*3+1] = accG + bg;
        out[ray*3+2] = accB + bg;
    }
}

extern "C" void kernel_launch(void* const* d_in, const int* in_sizes, int n_in,
                              void* d_out, int out_size, void* d_ws, size_t ws_size,
                              hipStream_t stream) {
    const float* rays_o = (const float*)d_in[0];
    const float* rays_d = (const float*)d_in[1];
    const float* sig    = (const float*)d_in[2];
    const float* rgb    = (const float*)d_in[3];
    float* out = (float*)d_out;
    plenoxel_render<<<NRAYS, 64, 0, stream>>>(rays_o, rays_d, sig, rgb, out);
}